// Round 4
// baseline (1235.982 us; speedup 1.0000x reference)
//
#include <hip/hip_runtime.h>
#include <hip/hip_bf16.h>

typedef __attribute__((ext_vector_type(4))) float  f32x4;
typedef __attribute__((ext_vector_type(8))) short  bf16x8;
typedef __attribute__((ext_vector_type(4))) float  float4v;
typedef __attribute__((ext_vector_type(8))) unsigned short ushort8;

#define CIO 128
#define BR  120          // out rows per CSR block (120*132*4 = 63360 B LDS)
#define CST 132          // accum row stride in floats; 2-way banks max (free)
#define TS  32           // entries per MFMA tile
#define NB_MAX 896       // LDS histogram bound in build kernels

__device__ __forceinline__ unsigned short f2bf(float f) {
  unsigned int u = __float_as_uint(f);
  u = u + 0x7fffu + ((u >> 16) & 1u);
  return (unsigned short)(u >> 16);
}
__device__ __forceinline__ float bf2f(unsigned short u) {
  return __uint_as_float(((unsigned int)u) << 16);
}

// ============ prep: Wswz[k][kb][nf][lane][8] = B-fragment order ============
// lane (l16,lk) of frag (k,nf,kb) holds Wt[k][nf*16+l16][kb*32+lk*8+e], e=0..7
// source W is [k][cin][cout] fp32.
__global__ void prep_wswz(const float* __restrict__ W,
                          unsigned short* __restrict__ Wswz, int total) {
  int i = blockIdx.x * 256 + threadIdx.x;   // one lane-slot (8 elems) each
  if (i >= total) return;
  int lane = i & 63;
  int nf   = (i >> 6) & 7;
  int kb   = (i >> 9) & 3;
  int k    = i >> 11;
  int n    = nf * 16 + (lane & 15);
  int c0   = kb * 32 + (lane >> 4) * 8;
  ushort8 v;
  #pragma unroll
  for (int e = 0; e < 8; ++e)
    v[e] = f2bf(W[k * 16384 + (c0 + e) * 128 + n]);
  *(ushort8*)(Wswz + (size_t)i * 8) = v;
}

// ============ prep: fbf = bf16(features) ============
__global__ void prep_fbf(const float* __restrict__ f,
                         unsigned short* __restrict__ fbf, int total8) {
  int i = blockIdx.x * 256 + threadIdx.x;
  if (i >= total8) return;
  const float4v* s = (const float4v*)(f + (size_t)i * 8);
  float4v v0 = s[0], v1 = s[1];
  ushort8 o;
  o[0] = f2bf(v0.x); o[1] = f2bf(v0.y); o[2] = f2bf(v0.z); o[3] = f2bf(v0.w);
  o[4] = f2bf(v1.x); o[5] = f2bf(v1.y); o[6] = f2bf(v1.z); o[7] = f2bf(v1.w);
  *(ushort8*)(fbf + (size_t)i * 8) = o;
}

// ============ build 1: per-k LDS histogram ============
__global__ __launch_bounds__(1024) void count27(const int* __restrict__ out_map,
                                                int* __restrict__ counts,
                                                int M, int NB) {
  __shared__ int h[NB_MAX];
  int k = blockIdx.x, t = threadIdx.x;
  for (int i = t; i < NB; i += 1024) h[i] = 0;
  __syncthreads();
  for (int m = t; m < M; m += 1024)
    atomicAdd(&h[out_map[k * M + m] / BR], 1);
  __syncthreads();
  for (int i = t; i < NB; i += 1024) counts[k * NB + i] = h[i];
}

// ============ build 2: exclusive scan over NKEY counts (1 block) ============
__global__ __launch_bounds__(1024) void scan_offsets(const int* __restrict__ counts,
                                                     int* __restrict__ offs, int nkey) {
  __shared__ int part[1024];
  int t = threadIdx.x;
  int chunk = (nkey + 1023) / 1024;
  int lo = t * chunk, hi = min(lo + chunk, nkey);
  int s = 0;
  for (int i = lo; i < hi; ++i) s += counts[i];
  part[t] = s;
  __syncthreads();
  for (int d = 1; d < 1024; d <<= 1) {
    int v = (t >= d) ? part[t - d] : 0;
    __syncthreads();
    part[t] += v;
    __syncthreads();
  }
  int run = (t > 0) ? part[t - 1] : 0;
  for (int i = lo; i < hi; ++i) { offs[i] = run; run += counts[i]; }
  if (t == 1023) offs[nkey] = part[1023];
}

// ============ build 3: per-k LDS-positioned scatter ============
__global__ __launch_bounds__(1024) void scatter27(const int* __restrict__ in_map,
                                                  const int* __restrict__ out_map,
                                                  const int* __restrict__ offs,
                                                  unsigned int* __restrict__ sorted,
                                                  int M, int NB) {
  __shared__ int pos[NB_MAX];
  int k = blockIdx.x, t = threadIdx.x;
  for (int i = t; i < NB; i += 1024) pos[i] = offs[k * NB + i];
  __syncthreads();
  for (int m = t; m < M; m += 1024) {
    int o = out_map[k * M + m];
    int p = atomicAdd(&pos[o / BR], 1);
    sorted[p] = ((unsigned int)in_map[k * M + m] << 7) | (unsigned int)(o % BR);
  }
}

// ============ main: CSR-tile MFMA, LDS fp32 accumulation, zero global atomics ============
template <bool FBF>
__global__ __launch_bounds__(512, 4) void spconv_csr(
    const float* __restrict__ features,
    const unsigned short* __restrict__ fbf,
    const unsigned short* __restrict__ Wswz,
    const unsigned int* __restrict__ sorted,
    const int* __restrict__ offs,
    const float* __restrict__ bias,
    float* __restrict__ out,
    int NB, int n_out, int KVOL) {
  __shared__ float accum[BR * CST];    // 63360 B
  const int b    = blockIdx.x;
  const int tid  = threadIdx.x;
  const int wave = tid >> 6;
  const int lane = tid & 63;
  const int l16  = lane & 15;
  const int lk   = lane >> 4;

  for (int i = tid; i < BR * CST; i += 512) accum[i] = 0.f;
  __syncthreads();

  int tc = 0;
  for (int k = 0; k < KVOL; ++k) {
    const int segS = offs[k * NB + b];
    const int segE = offs[k * NB + b + 1];
    const unsigned short* wk = Wswz + (size_t)k * 16384;
    int nt = (segE - segS + TS - 1) >> 5;
    for (int t = 0; t < nt; ++t) {
      if ((tc++ & 7) != wave) continue;
      int base = segS + (t << 5);
      int i0 = base + l16, i1 = base + 16 + l16;
      unsigned int w0 = (i0 < segE) ? sorted[i0] : 0u;
      unsigned int w1 = (i1 < segE) ? sorted[i1] : 0u;
      int in0 = (int)(w0 >> 7), in1 = (int)(w1 >> 7);

      f32x4 acc[2][8] = {};
      #pragma unroll
      for (int kb = 0; kb < 4; ++kb) {
        bf16x8 a0, a1;
        if (FBF) {
          a0 = *(const bf16x8*)(fbf + (size_t)in0 * CIO + kb * 32 + lk * 8);
          a1 = *(const bf16x8*)(fbf + (size_t)in1 * CIO + kb * 32 + lk * 8);
        } else {
          const float* p0 = features + (size_t)in0 * CIO + kb * 32 + lk * 8;
          const float* p1 = features + (size_t)in1 * CIO + kb * 32 + lk * 8;
          float4v u0 = *(const float4v*)p0, u1 = *(const float4v*)(p0 + 4);
          float4v u2 = *(const float4v*)p1, u3 = *(const float4v*)(p1 + 4);
          ushort8 t0, t1;
          t0[0]=f2bf(u0.x); t0[1]=f2bf(u0.y); t0[2]=f2bf(u0.z); t0[3]=f2bf(u0.w);
          t0[4]=f2bf(u1.x); t0[5]=f2bf(u1.y); t0[6]=f2bf(u1.z); t0[7]=f2bf(u1.w);
          t1[0]=f2bf(u2.x); t1[1]=f2bf(u2.y); t1[2]=f2bf(u2.z); t1[3]=f2bf(u2.w);
          t1[4]=f2bf(u3.x); t1[5]=f2bf(u3.y); t1[6]=f2bf(u3.z); t1[7]=f2bf(u3.w);
          a0 = *(bf16x8*)&t0; a1 = *(bf16x8*)&t1;
        }
        const unsigned short* wkb = wk + kb * 4096;
        #pragma unroll
        for (int nf = 0; nf < 8; ++nf) {
          bf16x8 bf = *(const bf16x8*)(wkb + nf * 512 + lane * 8);
          acc[0][nf] = __builtin_amdgcn_mfma_f32_16x16x32_bf16(a0, bf, acc[0][nf], 0, 0, 0);
          acc[1][nf] = __builtin_amdgcn_mfma_f32_16x16x32_bf16(a1, bf, acc[1][nf], 0, 0, 0);
        }
      }

      // D layout: row(entry) = rg*16 + lk*4 + r, col = nf*16 + l16
      #pragma unroll
      for (int rg = 0; rg < 2; ++rg) {
        unsigned int wsrc = rg ? w1 : w0;
        #pragma unroll
        for (int r = 0; r < 4; ++r) {
          int idx = base + rg * 16 + lk * 4 + r;
          if (idx < segE) {
            int lrow = (int)(__shfl(wsrc, lk * 4 + r) & 127u);
            float* dst = accum + lrow * CST + l16;
            #pragma unroll
            for (int nf = 0; nf < 8; ++nf)
              atomicAdd(dst + nf * 16, acc[rg][nf][r]);
          }
        }
      }
    }
  }
  __syncthreads();

  // store: out[b*BR + row][c] = accum[row][c] + bias[c]
  for (int i = tid; i < BR * 32; i += 512) {
    int row = i >> 5, c4 = i & 31;
    int orow = b * BR + row;
    if (orow < n_out) {
      float4v v  = *(const float4v*)(accum + row * CST + c4 * 4);
      float4v bi = ((const float4v*)bias)[c4];
      v.x += bi.x; v.y += bi.y; v.z += bi.z; v.w += bi.w;
      *(float4v*)(out + (size_t)orow * CIO + c4 * 4) = v;
    }
  }
}

// ===================== legacy fallback (R1, tiny-ws path) =====================
__global__ void prep_weights(const float* __restrict__ W,
                             unsigned short* __restrict__ Wt, int total) {
  int idx = blockIdx.x * 256 + threadIdx.x;
  if (idx >= total) return;
  int k  = idx >> 14;
  int n  = (idx >> 7) & 127;
  int kk = idx & 127;
  Wt[idx] = f2bf(W[k * 16384 + kk * 128 + n]);
}
__global__ void init_bias(float* __restrict__ out,
                          const float* __restrict__ bias, int total4) {
  int idx = blockIdx.x * 256 + threadIdx.x;
  if (idx >= total4) return;
  float4v b = ((const float4v*)bias)[idx & 31];
  ((float4v*)out)[idx] = b;
}
__global__ __launch_bounds__(256) void spconv_mfma_legacy(
    const float* __restrict__ features, const unsigned short* __restrict__ Wt,
    const int* __restrict__ in_map, const int* __restrict__ out_map,
    float* __restrict__ out, int M) {
  const int ky = blockIdx.y, m0 = blockIdx.x * 64, tid = threadIdx.x;
  __shared__ unsigned short Alds[64 * CIO];
  __shared__ unsigned short Blds[CIO * CIO];
  {
    const ushort8* src = (const ushort8*)(Wt + ky * 16384);
    #pragma unroll
    for (int i = 0; i < 8; ++i) {
      int chunk = tid + i * 256, byte = chunk * 16;
      int row = byte >> 8, off = byte & 255, sw = off ^ ((row & 7) << 4);
      *(ushort8*)((char*)Blds + row * 256 + sw) = src[chunk];
    }
  }
  {
    int r = tid >> 2, q = tid & 3, m = m0 + r;
    unsigned short tmp[32];
    if (m < M) {
      int frow = in_map[ky * M + m];
      const float4v* src = (const float4v*)(features + frow * CIO + q * 32);
      #pragma unroll
      for (int i = 0; i < 8; ++i) {
        float4v v = src[i];
        tmp[i*4+0]=f2bf(v.x); tmp[i*4+1]=f2bf(v.y); tmp[i*4+2]=f2bf(v.z); tmp[i*4+3]=f2bf(v.w);
      }
    } else {
      #pragma unroll
      for (int i = 0; i < 32; ++i) tmp[i] = 0;
    }
    #pragma unroll
    for (int c = 0; c < 4; ++c) {
      int off = q * 64 + c * 16, sw = off ^ ((r & 7) << 4);
      *(ushort8*)((char*)Alds + r * 256 + sw) = *(ushort8*)(tmp + c * 8);
    }
  }
  __syncthreads();
  const int wid = tid >> 6, lane = tid & 63;
  const int wm = wid >> 1, wn = wid & 1, l16 = lane & 15, lk = lane >> 4;
  f32x4 acc[2][4] = {};
  #pragma unroll
  for (int kb = 0; kb < CIO; kb += 32) {
    bf16x8 af[2], bfr[4];
    #pragma unroll
    for (int mf = 0; mf < 2; ++mf) {
      int row = wm * 32 + mf * 16 + l16, off = (kb + lk * 8) * 2;
      int sw = off ^ ((row & 7) << 4);
      af[mf] = *(const bf16x8*)((const char*)Alds + row * 256 + sw);
    }
    #pragma unroll
    for (int nf = 0; nf < 4; ++nf) {
      int n = wn * 64 + nf * 16 + l16, off = (kb + lk * 8) * 2;
      int sw = off ^ ((n & 7) << 4);
      bfr[nf] = *(const bf16x8*)((const char*)Blds + n * 256 + sw);
    }
    #pragma unroll
    for (int mf = 0; mf < 2; ++mf)
      #pragma unroll
      for (int nf = 0; nf < 4; ++nf)
        acc[mf][nf] = __builtin_amdgcn_mfma_f32_16x16x32_bf16(af[mf], bfr[nf], acc[mf][nf], 0, 0, 0);
  }
  #pragma unroll
  for (int mf = 0; mf < 2; ++mf)
    #pragma unroll
    for (int r = 0; r < 4; ++r) {
      int mrow = wm * 32 + mf * 16 + lk * 4 + r, m = m0 + mrow;
      if (m < M) {
        int orow = out_map[ky * M + m];
        float* dst = out + orow * CIO + wn * 64 + l16;
        #pragma unroll
        for (int nf = 0; nf < 4; ++nf) unsafeAtomicAdd(dst + nf * 16, acc[mf][nf][r]);
      }
    }
}

static inline size_t align256(size_t x) { return (x + 255) & ~(size_t)255; }

extern "C" void kernel_launch(void* const* d_in, const int* in_sizes, int n_in,
                              void* d_out, int out_size, void* d_ws, size_t ws_size,
                              hipStream_t stream) {
  const float* features = (const float*)d_in[0];
  const float* W        = (const float*)d_in[1];
  const float* bias     = (const float*)d_in[2];
  const int*   in_map   = (const int*)d_in[3];
  const int*   out_map  = (const int*)d_in[4];
  float*       out      = (float*)d_out;

  const int KVOL  = in_sizes[1] / (CIO * CIO);     // 27
  const int M     = in_sizes[3] / KVOL;            // 50000
  const int n_out = out_size / CIO;                // 100000
  const int N_IN  = in_sizes[0] / CIO;             // 100000
  const int NB    = (n_out + BR - 1) / BR;         // 834
  const int NKEY  = KVOL * NB;
  const size_t KM = (size_t)KVOL * M;              // 1.35M

  const size_t s_wswz = (size_t)KVOL * CIO * CIO * 2;
  const size_t o_cnt  = align256(s_wswz);
  const size_t o_offs = align256(o_cnt + (size_t)NKEY * 4);
  const size_t o_sort = align256(o_offs + ((size_t)NKEY + 1) * 4);
  const size_t o_fbf  = align256(o_sort + KM * 4);
  const size_t need_mid  = o_fbf;
  const size_t need_full = o_fbf + (size_t)N_IN * CIO * 2;

  if (NB <= NB_MAX && ws_size >= need_mid) {
    unsigned short* Wswz  = (unsigned short*)d_ws;
    int*            cnt   = (int*)((char*)d_ws + o_cnt);
    int*            offs  = (int*)((char*)d_ws + o_offs);
    unsigned int*   sorted= (unsigned int*)((char*)d_ws + o_sort);
    unsigned short* fbf   = (unsigned short*)((char*)d_ws + o_fbf);
    const bool full = (ws_size >= need_full);

    int wtot = KVOL * 4 * 8 * 64;
    prep_wswz<<<(wtot + 255) / 256, 256, 0, stream>>>(W, Wswz, wtot);
    if (full) {
      int total8 = N_IN * CIO / 8;
      prep_fbf<<<(total8 + 255) / 256, 256, 0, stream>>>(features, fbf, total8);
    }
    count27<<<KVOL, 1024, 0, stream>>>(out_map, cnt, M, NB);
    scan_offsets<<<1, 1024, 0, stream>>>(cnt, offs, NKEY);
    scatter27<<<KVOL, 1024, 0, stream>>>(in_map, out_map, offs, sorted, M, NB);

    if (full)
      spconv_csr<true><<<NB, 512, 0, stream>>>(features, fbf, Wswz, sorted, offs,
                                               bias, out, NB, n_out, KVOL);
    else
      spconv_csr<false><<<NB, 512, 0, stream>>>(features, fbf, Wswz, sorted, offs,
                                                bias, out, NB, n_out, KVOL);
  } else {
    // legacy tiny-ws fallback
    unsigned short* Wt = (unsigned short*)d_ws;
    if (ws_size < s_wswz) return;
    int wtot = KVOL * CIO * CIO;
    prep_weights<<<(wtot + 255) / 256, 256, 0, stream>>>(W, Wt, wtot);
    int total4 = out_size / 4;
    init_bias<<<(total4 + 255) / 256, 256, 0, stream>>>(out, bias, total4);
    dim3 grid((M + 63) / 64, KVOL);
    spconv_mfma_legacy<<<grid, 256, 0, stream>>>(features, Wt, in_map, out_map, out, M);
  }
}

// Round 5
// 1211.357 us; speedup vs baseline: 1.0203x; 1.0203x over previous
//
#include <hip/hip_runtime.h>
#include <hip/hip_bf16.h>

typedef __attribute__((ext_vector_type(4))) float  f32x4;
typedef __attribute__((ext_vector_type(8))) short  bf16x8;
typedef __attribute__((ext_vector_type(4))) float  float4v;
typedef __attribute__((ext_vector_type(8))) unsigned short ushort8;

#define CIO 128
#define BR  120          // out rows per CSR block (120*132*4 = 63360 B LDS)
#define CST 132          // accum row stride in floats; max 2-way banks (free)
#define TS  32           // entries per MFMA tile
#define NB_MAX 896       // LDS histogram bound in build kernels

__device__ __forceinline__ unsigned short f2bf(float f) {
  unsigned int u = __float_as_uint(f);
  u = u + 0x7fffu + ((u >> 16) & 1u);
  return (unsigned short)(u >> 16);
}
__device__ __forceinline__ float bf2f(unsigned short u) {
  return __uint_as_float(((unsigned int)u) << 16);
}

// ============ prep: Wswz[k][kb][nf][lane][8] = B-fragment order ============
__global__ void prep_wswz(const float* __restrict__ W,
                          unsigned short* __restrict__ Wswz, int total) {
  int i = blockIdx.x * 256 + threadIdx.x;
  if (i >= total) return;
  int lane = i & 63;
  int nf   = (i >> 6) & 7;
  int kb   = (i >> 9) & 3;
  int k    = i >> 11;
  int n    = nf * 16 + (lane & 15);
  int c0   = kb * 32 + (lane >> 4) * 8;
  ushort8 v;
  #pragma unroll
  for (int e = 0; e < 8; ++e)
    v[e] = f2bf(W[k * 16384 + (c0 + e) * 128 + n]);
  *(ushort8*)(Wswz + (size_t)i * 8) = v;
}

// ============ prep: fbf = bf16(features) ============
__global__ void prep_fbf(const float* __restrict__ f,
                         unsigned short* __restrict__ fbf, int total8) {
  int i = blockIdx.x * 256 + threadIdx.x;
  if (i >= total8) return;
  const float4v* s = (const float4v*)(f + (size_t)i * 8);
  float4v v0 = s[0], v1 = s[1];
  ushort8 o;
  o[0] = f2bf(v0.x); o[1] = f2bf(v0.y); o[2] = f2bf(v0.z); o[3] = f2bf(v0.w);
  o[4] = f2bf(v1.x); o[5] = f2bf(v1.y); o[6] = f2bf(v1.z); o[7] = f2bf(v1.w);
  *(ushort8*)(fbf + (size_t)i * 8) = o;
}

// ============ build 1: per-k LDS histogram ============
__global__ __launch_bounds__(1024) void count27(const int* __restrict__ out_map,
                                                int* __restrict__ counts,
                                                int M, int NB) {
  __shared__ int h[NB_MAX];
  int k = blockIdx.x, t = threadIdx.x;
  for (int i = t; i < NB; i += 1024) h[i] = 0;
  __syncthreads();
  for (int m = t; m < M; m += 1024)
    atomicAdd(&h[out_map[k * M + m] / BR], 1);
  __syncthreads();
  for (int i = t; i < NB; i += 1024) counts[k * NB + i] = h[i];
}

// ============ build 2: exclusive scan over NKEY counts (1 block) ============
__global__ __launch_bounds__(1024) void scan_offsets(const int* __restrict__ counts,
                                                     int* __restrict__ offs, int nkey) {
  __shared__ int part[1024];
  int t = threadIdx.x;
  int chunk = (nkey + 1023) / 1024;
  int lo = t * chunk, hi = min(lo + chunk, nkey);
  int s = 0;
  for (int i = lo; i < hi; ++i) s += counts[i];
  part[t] = s;
  __syncthreads();
  for (int d = 1; d < 1024; d <<= 1) {
    int v = (t >= d) ? part[t - d] : 0;
    __syncthreads();
    part[t] += v;
    __syncthreads();
  }
  int run = (t > 0) ? part[t - 1] : 0;
  for (int i = lo; i < hi; ++i) { offs[i] = run; run += counts[i]; }
  if (t == 1023) offs[nkey] = part[1023];
}

// ============ build 3: per-k LDS-positioned scatter ============
__global__ __launch_bounds__(1024) void scatter27(const int* __restrict__ in_map,
                                                  const int* __restrict__ out_map,
                                                  const int* __restrict__ offs,
                                                  unsigned int* __restrict__ sorted,
                                                  int M, int NB) {
  __shared__ int pos[NB_MAX];
  int k = blockIdx.x, t = threadIdx.x;
  for (int i = t; i < NB; i += 1024) pos[i] = offs[k * NB + i];
  __syncthreads();
  for (int m = t; m < M; m += 1024) {
    int o = out_map[k * M + m];
    int p = atomicAdd(&pos[o / BR], 1);
    sorted[p] = ((unsigned int)in_map[k * M + m] << 7) | (unsigned int)(o % BR);
  }
}

// ============ main: CSR-tile MFMA, LDS fp32 accumulation ============
// Register discipline (R4 spilled at acc[2][8]): A-frags cached (32 VGPR),
// N split into two halves so only acc[2][4] (32 VGPR) is live at a time.
template <bool FBF>
__global__ __launch_bounds__(512, 4) void spconv_csr(
    const float* __restrict__ features,
    const unsigned short* __restrict__ fbf,
    const unsigned short* __restrict__ Wswz,
    const unsigned int* __restrict__ sorted,
    const int* __restrict__ offs,
    const float* __restrict__ bias,
    float* __restrict__ out,
    int NB, int n_out, int KVOL) {
  __shared__ float accum[BR * CST];    // 63360 B
  const int b    = blockIdx.x;
  const int tid  = threadIdx.x;
  const int wave = tid >> 6;
  const int lane = tid & 63;
  const int l16  = lane & 15;
  const int lk   = lane >> 4;

  for (int i = tid; i < BR * CST; i += 512) accum[i] = 0.f;
  __syncthreads();

  int tc = 0;
  for (int k = 0; k < KVOL; ++k) {
    const int segS = offs[k * NB + b];
    const int segE = offs[k * NB + b + 1];
    const unsigned short* wk = Wswz + (size_t)k * 16384;
    int nt = (segE - segS + TS - 1) >> 5;
    for (int t = 0; t < nt; ++t) {
      if ((tc++ & 7) != wave) continue;
      int base = segS + (t << 5);
      int i0 = base + l16, i1 = base + 16 + l16;
      unsigned int w0 = (i0 < segE) ? sorted[i0] : 0u;
      unsigned int w1 = (i1 < segE) ? sorted[i1] : 0u;
      int in0 = (int)(w0 >> 7), in1 = (int)(w1 >> 7);

      // ---- gather A-frags for both 16-row groups, all 4 k-blocks ----
      bf16x8 a[2][4];
      if (FBF) {
        #pragma unroll
        for (int kb = 0; kb < 4; ++kb) {
          a[0][kb] = *(const bf16x8*)(fbf + (size_t)in0 * CIO + kb * 32 + lk * 8);
          a[1][kb] = *(const bf16x8*)(fbf + (size_t)in1 * CIO + kb * 32 + lk * 8);
        }
      } else {
        #pragma unroll
        for (int kb = 0; kb < 4; ++kb) {
          const float* p0 = features + (size_t)in0 * CIO + kb * 32 + lk * 8;
          const float* p1 = features + (size_t)in1 * CIO + kb * 32 + lk * 8;
          float4v u0 = *(const float4v*)p0, u1 = *(const float4v*)(p0 + 4);
          float4v u2 = *(const float4v*)p1, u3 = *(const float4v*)(p1 + 4);
          ushort8 t0, t1;
          t0[0]=f2bf(u0.x); t0[1]=f2bf(u0.y); t0[2]=f2bf(u0.z); t0[3]=f2bf(u0.w);
          t0[4]=f2bf(u1.x); t0[5]=f2bf(u1.y); t0[6]=f2bf(u1.z); t0[7]=f2bf(u1.w);
          t1[0]=f2bf(u2.x); t1[1]=f2bf(u2.y); t1[2]=f2bf(u2.z); t1[3]=f2bf(u2.w);
          t1[4]=f2bf(u3.x); t1[5]=f2bf(u3.y); t1[6]=f2bf(u3.z); t1[7]=f2bf(u3.w);
          a[0][kb] = *(bf16x8*)&t0; a[1][kb] = *(bf16x8*)&t1;
        }
      }

      // ---- two N-halves: acc[2][4] live at a time (32 VGPRs) ----
      #pragma unroll
      for (int h = 0; h < 2; ++h) {
        f32x4 acc[2][4] = {};
        #pragma unroll
        for (int kb = 0; kb < 4; ++kb) {
          const unsigned short* wkb = wk + kb * 4096 + h * 2048;
          #pragma unroll
          for (int nf = 0; nf < 4; ++nf) {
            bf16x8 bf = *(const bf16x8*)(wkb + nf * 512 + lane * 8);
            acc[0][nf] = __builtin_amdgcn_mfma_f32_16x16x32_bf16(a[0][kb], bf, acc[0][nf], 0, 0, 0);
            acc[1][nf] = __builtin_amdgcn_mfma_f32_16x16x32_bf16(a[1][kb], bf, acc[1][nf], 0, 0, 0);
          }
        }
        // D layout: row(entry) = rg*16 + lk*4 + r, col = (h*4+nf)*16 + l16
        #pragma unroll
        for (int rg = 0; rg < 2; ++rg) {
          unsigned int wsrc = rg ? w1 : w0;
          #pragma unroll
          for (int r = 0; r < 4; ++r) {
            int idx = base + rg * 16 + lk * 4 + r;
            if (idx < segE) {
              int lrow = (int)(__shfl(wsrc, lk * 4 + r) & 127u);
              float* dst = accum + lrow * CST + h * 64 + l16;
              #pragma unroll
              for (int nf = 0; nf < 4; ++nf)
                atomicAdd(dst + nf * 16, acc[rg][nf][r]);
            }
          }
        }
        __builtin_amdgcn_sched_barrier(0);   // keep halves separate: cap reg peak
      }
    }
  }
  __syncthreads();

  // store: out[b*BR + row][c] = accum[row][c] + bias[c]
  for (int i = tid; i < BR * 32; i += 512) {
    int row = i >> 5, c4 = i & 31;
    int orow = b * BR + row;
    if (orow < n_out) {
      float4v v  = *(const float4v*)(accum + row * CST + c4 * 4);
      float4v bi = ((const float4v*)bias)[c4];
      v.x += bi.x; v.y += bi.y; v.z += bi.z; v.w += bi.w;
      *(float4v*)(out + (size_t)orow * CIO + c4 * 4) = v;
    }
  }
}

// ===================== legacy fallback (R1, tiny-ws path) =====================
__global__ void prep_weights(const float* __restrict__ W,
                             unsigned short* __restrict__ Wt, int total) {
  int idx = blockIdx.x * 256 + threadIdx.x;
  if (idx >= total) return;
  int k  = idx >> 14;
  int n  = (idx >> 7) & 127;
  int kk = idx & 127;
  Wt[idx] = f2bf(W[k * 16384 + kk * 128 + n]);
}
__global__ void init_bias(float* __restrict__ out,
                          const float* __restrict__ bias, int total4) {
  int idx = blockIdx.x * 256 + threadIdx.x;
  if (idx >= total4) return;
  float4v b = ((const float4v*)bias)[idx & 31];
  ((float4v*)out)[idx] = b;
}
__global__ __launch_bounds__(256) void spconv_mfma_legacy(
    const float* __restrict__ features, const unsigned short* __restrict__ Wt,
    const int* __restrict__ in_map, const int* __restrict__ out_map,
    float* __restrict__ out, int M) {
  const int ky = blockIdx.y, m0 = blockIdx.x * 64, tid = threadIdx.x;
  __shared__ unsigned short Alds[64 * CIO];
  __shared__ unsigned short Blds[CIO * CIO];
  {
    const ushort8* src = (const ushort8*)(Wt + ky * 16384);
    #pragma unroll
    for (int i = 0; i < 8; ++i) {
      int chunk = tid + i * 256, byte = chunk * 16;
      int row = byte >> 8, off = byte & 255, sw = off ^ ((row & 7) << 4);
      *(ushort8*)((char*)Blds + row * 256 + sw) = src[chunk];
    }
  }
  {
    int r = tid >> 2, q = tid & 3, m = m0 + r;
    unsigned short tmp[32];
    if (m < M) {
      int frow = in_map[ky * M + m];
      const float4v* src = (const float4v*)(features + frow * CIO + q * 32);
      #pragma unroll
      for (int i = 0; i < 8; ++i) {
        float4v v = src[i];
        tmp[i*4+0]=f2bf(v.x); tmp[i*4+1]=f2bf(v.y); tmp[i*4+2]=f2bf(v.z); tmp[i*4+3]=f2bf(v.w);
      }
    } else {
      #pragma unroll
      for (int i = 0; i < 32; ++i) tmp[i] = 0;
    }
    #pragma unroll
    for (int c = 0; c < 4; ++c) {
      int off = q * 64 + c * 16, sw = off ^ ((r & 7) << 4);
      *(ushort8*)((char*)Alds + r * 256 + sw) = *(ushort8*)(tmp + c * 8);
    }
  }
  __syncthreads();
  const int wid = tid >> 6, lane = tid & 63;
  const int wm = wid >> 1, wn = wid & 1, l16 = lane & 15, lk = lane >> 4;
  f32x4 acc[2][4] = {};
  #pragma unroll
  for (int kb = 0; kb < CIO; kb += 32) {
    bf16x8 af[2], bfr[4];
    #pragma unroll
    for (int mf = 0; mf < 2; ++mf) {
      int row = wm * 32 + mf * 16 + l16, off = (kb + lk * 8) * 2;
      int sw = off ^ ((row & 7) << 4);
      af[mf] = *(const bf16x8*)((const char*)Alds + row * 256 + sw);
    }
    #pragma unroll
    for (int nf = 0; nf < 4; ++nf) {
      int n = wn * 64 + nf * 16 + l16, off = (kb + lk * 8) * 2;
      int sw = off ^ ((n & 7) << 4);
      bfr[nf] = *(const bf16x8*)((const char*)Blds + n * 256 + sw);
    }
    #pragma unroll
    for (int mf = 0; mf < 2; ++mf)
      #pragma unroll
      for (int nf = 0; nf < 4; ++nf)
        acc[mf][nf] = __builtin_amdgcn_mfma_f32_16x16x32_bf16(af[mf], bfr[nf], acc[mf][nf], 0, 0, 0);
  }
  #pragma unroll
  for (int mf = 0; mf < 2; ++mf)
    #pragma unroll
    for (int r = 0; r < 4; ++r) {
      int mrow = wm * 32 + mf * 16 + lk * 4 + r, m = m0 + mrow;
      if (m < M) {
        int orow = out_map[ky * M + m];
        float* dst = out + orow * CIO + wn * 64 + l16;
        #pragma unroll
        for (int nf = 0; nf < 4; ++nf) unsafeAtomicAdd(dst + nf * 16, acc[mf][nf][r]);
      }
    }
}

static inline size_t align256(size_t x) { return (x + 255) & ~(size_t)255; }

extern "C" void kernel_launch(void* const* d_in, const int* in_sizes, int n_in,
                              void* d_out, int out_size, void* d_ws, size_t ws_size,
                              hipStream_t stream) {
  const float* features = (const float*)d_in[0];
  const float* W        = (const float*)d_in[1];
  const float* bias     = (const float*)d_in[2];
  const int*   in_map   = (const int*)d_in[3];
  const int*   out_map  = (const int*)d_in[4];
  float*       out      = (float*)d_out;

  const int KVOL  = in_sizes[1] / (CIO * CIO);     // 27
  const int M     = in_sizes[3] / KVOL;            // 50000
  const int n_out = out_size / CIO;                // 100000
  const int N_IN  = in_sizes[0] / CIO;             // 100000
  const int NB    = (n_out + BR - 1) / BR;         // 834
  const int NKEY  = KVOL * NB;
  const size_t KM = (size_t)KVOL * M;              // 1.35M

  const size_t s_wswz = (size_t)KVOL * CIO * CIO * 2;
  const size_t o_cnt  = align256(s_wswz);
  const size_t o_offs = align256(o_cnt + (size_t)NKEY * 4);
  const size_t o_sort = align256(o_offs + ((size_t)NKEY + 1) * 4);
  const size_t o_fbf  = align256(o_sort + KM * 4);
  const size_t need_mid  = o_fbf;
  const size_t need_full = o_fbf + (size_t)N_IN * CIO * 2;

  if (NB <= NB_MAX && ws_size >= need_mid) {
    unsigned short* Wswz  = (unsigned short*)d_ws;
    int*            cnt   = (int*)((char*)d_ws + o_cnt);
    int*            offs  = (int*)((char*)d_ws + o_offs);
    unsigned int*   sorted= (unsigned int*)((char*)d_ws + o_sort);
    unsigned short* fbf   = (unsigned short*)((char*)d_ws + o_fbf);
    const bool full = (ws_size >= need_full);

    int wtot = KVOL * 4 * 8 * 64;
    prep_wswz<<<(wtot + 255) / 256, 256, 0, stream>>>(W, Wswz, wtot);
    if (full) {
      int total8 = N_IN * CIO / 8;
      prep_fbf<<<(total8 + 255) / 256, 256, 0, stream>>>(features, fbf, total8);
    }
    count27<<<KVOL, 1024, 0, stream>>>(out_map, cnt, M, NB);
    scan_offsets<<<1, 1024, 0, stream>>>(cnt, offs, NKEY);
    scatter27<<<KVOL, 1024, 0, stream>>>(in_map, out_map, offs, sorted, M, NB);

    if (full)
      spconv_csr<true><<<NB, 512, 0, stream>>>(features, fbf, Wswz, sorted, offs,
                                               bias, out, NB, n_out, KVOL);
    else
      spconv_csr<false><<<NB, 512, 0, stream>>>(features, fbf, Wswz, sorted, offs,
                                                bias, out, NB, n_out, KVOL);
  } else {
    // legacy tiny-ws fallback
    unsigned short* Wt = (unsigned short*)d_ws;
    if (ws_size < s_wswz) return;
    int wtot = KVOL * CIO * CIO;
    prep_weights<<<(wtot + 255) / 256, 256, 0, stream>>>(W, Wt, wtot);
    int total4 = out_size / 4;
    init_bias<<<(total4 + 255) / 256, 256, 0, stream>>>(out, bias, total4);
    dim3 grid((M + 63) / 64, KVOL);
    spconv_mfma_legacy<<<grid, 256, 0, stream>>>(features, Wt, in_map, out_map, out, M);
  }
}

// Round 6
// 573.772 us; speedup vs baseline: 2.1541x; 2.1112x over previous
//
#include <hip/hip_runtime.h>
#include <hip/hip_bf16.h>

typedef __attribute__((ext_vector_type(4))) float  f32x4;
typedef __attribute__((ext_vector_type(8))) short  bf16x8;
typedef __attribute__((ext_vector_type(4))) float  float4v;
typedef __attribute__((ext_vector_type(8))) unsigned short ushort8;
typedef __attribute__((ext_vector_type(4))) unsigned short ushort4v;

#define CIO 128
#define BR  120          // out rows per bucket/block
#define NB_MAX 896       // LDS histogram bound in build kernels
#define MAXE 2048        // phase-B per-block entry bound (mean 1620, sd ~40)

__device__ __forceinline__ unsigned short f2bf(float f) {
  unsigned int u = __float_as_uint(f);
  u = u + 0x7fffu + ((u >> 16) & 1u);
  return (unsigned short)(u >> 16);
}
__device__ __forceinline__ float bf2f(unsigned short u) {
  return __uint_as_float(((unsigned int)u) << 16);
}

// ============ prep: Wswz[k][kb][nf][lane][8] = B-fragment order ============
__global__ void prep_wswz(const float* __restrict__ W,
                          unsigned short* __restrict__ Wswz, int total) {
  int i = blockIdx.x * 256 + threadIdx.x;
  if (i >= total) return;
  int lane = i & 63;
  int nf   = (i >> 6) & 7;
  int kb   = (i >> 9) & 3;
  int k    = i >> 11;
  int n    = nf * 16 + (lane & 15);
  int c0   = kb * 32 + (lane >> 4) * 8;
  ushort8 v;
  #pragma unroll
  for (int e = 0; e < 8; ++e)
    v[e] = f2bf(W[k * 16384 + (c0 + e) * 128 + n]);
  *(ushort8*)(Wswz + (size_t)i * 8) = v;
}

// ============ prep: fbf = bf16(features) ============
__global__ void prep_fbf(const float* __restrict__ f,
                         unsigned short* __restrict__ fbf, int total8) {
  int i = blockIdx.x * 256 + threadIdx.x;
  if (i >= total8) return;
  const float4v* s = (const float4v*)(f + (size_t)i * 8);
  float4v v0 = s[0], v1 = s[1];
  ushort8 o;
  o[0] = f2bf(v0.x); o[1] = f2bf(v0.y); o[2] = f2bf(v0.z); o[3] = f2bf(v0.w);
  o[4] = f2bf(v1.x); o[5] = f2bf(v1.y); o[6] = f2bf(v1.z); o[7] = f2bf(v1.w);
  *(ushort8*)(fbf + (size_t)i * 8) = o;
}

// ============ build 1: per-k LDS histogram over 120-row buckets ============
__global__ __launch_bounds__(1024) void count27(const int* __restrict__ out_map,
                                                int* __restrict__ counts,
                                                int M, int NB) {
  __shared__ int h[NB_MAX];
  int k = blockIdx.x, t = threadIdx.x;
  for (int i = t; i < NB; i += 1024) h[i] = 0;
  __syncthreads();
  for (int m = t; m < M; m += 1024)
    atomicAdd(&h[out_map[k * M + m] / BR], 1);
  __syncthreads();
  for (int i = t; i < NB; i += 1024) counts[k * NB + i] = h[i];
}

// ============ build 2: exclusive scan over NKEY counts (1 block) ============
__global__ __launch_bounds__(1024) void scan_offsets(const int* __restrict__ counts,
                                                     int* __restrict__ offs, int nkey) {
  __shared__ int part[1024];
  int t = threadIdx.x;
  int chunk = (nkey + 1023) / 1024;
  int lo = t * chunk, hi = min(lo + chunk, nkey);
  int s = 0;
  for (int i = lo; i < hi; ++i) s += counts[i];
  part[t] = s;
  __syncthreads();
  for (int d = 1; d < 1024; d <<= 1) {
    int v = (t >= d) ? part[t - d] : 0;
    __syncthreads();
    part[t] += v;
    __syncthreads();
  }
  int run = (t > 0) ? part[t - 1] : 0;
  for (int i = lo; i < hi; ++i) { offs[i] = run; run += counts[i]; }
  if (t == 1023) offs[nkey] = part[1023];
}

// ============ build 3: per-k LDS-positioned scatter ============
__global__ __launch_bounds__(1024) void scatter27(const int* __restrict__ in_map,
                                                  const int* __restrict__ out_map,
                                                  const int* __restrict__ offs,
                                                  unsigned int* __restrict__ sorted,
                                                  int M, int NB) {
  __shared__ int pos[NB_MAX];
  int k = blockIdx.x, t = threadIdx.x;
  for (int i = t; i < NB; i += 1024) pos[i] = offs[k * NB + i];
  __syncthreads();
  for (int m = t; m < M; m += 1024) {
    int o = out_map[k * M + m];
    int p = atomicAdd(&pos[o / BR], 1);
    sorted[p] = ((unsigned int)in_map[k * M + m] << 7) | (unsigned int)(o % BR);
  }
}

// ============ PHASE A: per-k gathered GEMM -> linear bf16 prod rows ============
// One wave per 32-entry tile. No cross-wave LDS, no barriers, no atomics.
__global__ __launch_bounds__(256) void spconv_prod(
    const unsigned short* __restrict__ fbf,
    const unsigned short* __restrict__ Wswz,
    const unsigned int* __restrict__ sorted,
    unsigned short* __restrict__ prod,     // chunk-relative rows
    int M, int TPK, int k0, int k1) {
  __shared__ unsigned short dtile[4][4096];   // per-wave 32x128 bf16
  const int wave = threadIdx.x >> 6;
  const int lane = threadIdx.x & 63;
  const int l16  = lane & 15;
  const int lk   = lane >> 4;
  const int g    = blockIdx.x * 4 + wave;
  const int nk   = k1 - k0;
  if (g >= nk * TPK) return;
  const int  k     = k0 + g / TPK;
  const int  t     = g - (g / TPK) * TPK;
  const long jbase = (long)k * M + (long)t * 32;
  const long kend  = (long)(k + 1) * M;
  const long pbase = (long)k0 * M;

  long i0 = jbase + l16, i1 = jbase + 16 + l16;
  unsigned int w0 = (i0 < kend) ? sorted[i0] : 0u;
  unsigned int w1 = (i1 < kend) ? sorted[i1] : 0u;
  int in0 = (int)(w0 >> 7), in1 = (int)(w1 >> 7);

  bf16x8 a[2][4];
  #pragma unroll
  for (int kb = 0; kb < 4; ++kb) {
    a[0][kb] = *(const bf16x8*)(fbf + (size_t)in0 * CIO + kb * 32 + lk * 8);
    a[1][kb] = *(const bf16x8*)(fbf + (size_t)in1 * CIO + kb * 32 + lk * 8);
  }

  const unsigned short* wk = Wswz + (size_t)k * 16384;
  #pragma unroll
  for (int h = 0; h < 2; ++h) {
    f32x4 acc[2][4] = {};
    #pragma unroll
    for (int kb = 0; kb < 4; ++kb) {
      const unsigned short* wkb = wk + kb * 4096 + h * 2048;
      #pragma unroll
      for (int nf = 0; nf < 4; ++nf) {
        bf16x8 bfr = *(const bf16x8*)(wkb + nf * 512 + lane * 8);
        acc[0][nf] = __builtin_amdgcn_mfma_f32_16x16x32_bf16(a[0][kb], bfr, acc[0][nf], 0, 0, 0);
        acc[1][nf] = __builtin_amdgcn_mfma_f32_16x16x32_bf16(a[1][kb], bfr, acc[1][nf], 0, 0, 0);
      }
    }
    // transpose to LDS: D row m = rg*16+lk*4+r, col c = h*64+nf*16+l16
    // swizzle c ^= ((m>>2)&3)<<4  -> 2-way max on write and read
    #pragma unroll
    for (int rg = 0; rg < 2; ++rg)
      #pragma unroll
      for (int r = 0; r < 4; ++r) {
        int m = rg * 16 + lk * 4 + r;
        #pragma unroll
        for (int nf = 0; nf < 4; ++nf) {
          int c = h * 64 + nf * 16 + l16;
          dtile[wave][m * 128 + (c ^ (lk << 4))] = f2bf(acc[rg][nf][r]);
        }
      }
  }
  // cross-lane LDS dependency within the wave: explicit wait (rule #18)
  asm volatile("s_waitcnt lgkmcnt(0)" ::: "memory");
  __builtin_amdgcn_sched_barrier(0);
  // linear coalesced store: 32 rows x 256B
  #pragma unroll
  for (int it = 0; it < 16; ++it) {
    int i  = it * 64 + lane;
    int m  = i >> 5;
    int c0 = (i & 31) * 4;
    int ad = m * 128 + (c0 ^ (((m >> 2) & 3) << 4));
    if (jbase + m < kend) {
      ushort4v v = *(const ushort4v*)&dtile[wave][ad];
      *(ushort4v*)(prod + (size_t)(jbase - pbase + m) * CIO + c0) = v;
    }
  }
}

// ============ PHASE B: per-bucket exact sort + register reduce ============
__global__ __launch_bounds__(256) void spconv_reduce(
    const unsigned short* __restrict__ prod,
    const unsigned int* __restrict__ sorted,
    const int* __restrict__ offs,
    const float* __restrict__ bias,
    float* __restrict__ out,
    int NB, int n_out, int M, int k0, int k1, int accum) {
  __shared__ int            jlist[MAXE];
  __shared__ unsigned short permv[MAXE];
  __shared__ unsigned char  lrowv[MAXE];
  __shared__ int rowcnt[BR], rowstart[BR + 1], rowfill[BR];
  __shared__ int segbase[32];
  const int b = blockIdx.x, tid = threadIdx.x;
  const int nk = k1 - k0;

  if (tid == 0) {
    int run = 0;
    for (int kk = 0; kk < nk; ++kk) {
      segbase[kk] = run;
      run += offs[(k0 + kk) * NB + b + 1] - offs[(k0 + kk) * NB + b];
    }
    segbase[nk] = run;
  }
  for (int i = tid; i < BR; i += 256) { rowcnt[i] = 0; rowfill[i] = 0; }
  __syncthreads();
  const int total = min(segbase[nk], MAXE);

  for (int kk = 0; kk < nk; ++kk) {
    int s0  = offs[(k0 + kk) * NB + b];
    int len = segbase[kk + 1] - segbase[kk];
    for (int i = tid; i < len; i += 256) {
      int pos = segbase[kk] + i;
      if (pos < MAXE) {
        unsigned int u = sorted[s0 + i];
        jlist[pos] = (s0 + i) - (int)((long)k0 * M);   // chunk-relative prod row
        lrowv[pos] = (unsigned char)(u & 127u);
        atomicAdd(&rowcnt[u & 127u], 1);
      }
    }
  }
  __syncthreads();
  if (tid == 0) {
    int run = 0;
    for (int r = 0; r < BR; ++r) { rowstart[r] = run; run += rowcnt[r]; }
    rowstart[BR] = run;
  }
  __syncthreads();
  for (int e = tid; e < total; e += 256) {
    int r = lrowv[e];
    int slot = rowstart[r] + atomicAdd(&rowfill[r], 1);
    permv[slot] = (unsigned short)e;
  }
  __syncthreads();

  const int c8 = tid & 31;    // 4-channel group
  const int rq = tid >> 5;    // row quad 0..7
  for (int r = rq; r < BR; r += 8) {
    float ax = 0.f, ay = 0.f, az = 0.f, aw = 0.f;
    int s0 = rowstart[r], s1 = rowstart[r + 1];
    for (int s = s0; s < s1; ++s) {
      int j = jlist[permv[s]];
      ushort4v v = *(const ushort4v*)(prod + (size_t)j * CIO + c8 * 4);
      ax += bf2f(v.x); ay += bf2f(v.y); az += bf2f(v.z); aw += bf2f(v.w);
    }
    int orow = b * BR + r;
    if (orow < n_out) {
      float4v o;
      if (accum) {
        float4v pv = *(const float4v*)(out + (size_t)orow * CIO + c8 * 4);
        o.x = pv.x + ax; o.y = pv.y + ay; o.z = pv.z + az; o.w = pv.w + aw;
      } else {
        float4v bi = ((const float4v*)bias)[c8];
        o.x = bi.x + ax; o.y = bi.y + ay; o.z = bi.z + az; o.w = bi.w + aw;
      }
      *(float4v*)(out + (size_t)orow * CIO + c8 * 4) = o;
    }
  }
}

// ===================== R5 CSR fallback (mid ws) =====================
template <bool FBF>
__global__ __launch_bounds__(512, 4) void spconv_csr(
    const float* __restrict__ features,
    const unsigned short* __restrict__ fbf,
    const unsigned short* __restrict__ Wswz,
    const unsigned int* __restrict__ sorted,
    const int* __restrict__ offs,
    const float* __restrict__ bias,
    float* __restrict__ out,
    int NB, int n_out, int KVOL) {
  __shared__ float accum[BR * 132];
  const int b    = blockIdx.x;
  const int tid  = threadIdx.x;
  const int wave = tid >> 6;
  const int lane = tid & 63;
  const int l16  = lane & 15;
  const int lk   = lane >> 4;
  for (int i = tid; i < BR * 132; i += 512) accum[i] = 0.f;
  __syncthreads();
  int tc = 0;
  for (int k = 0; k < KVOL; ++k) {
    const int segS = offs[k * NB + b];
    const int segE = offs[k * NB + b + 1];
    const unsigned short* wk = Wswz + (size_t)k * 16384;
    int nt = (segE - segS + 31) >> 5;
    for (int t = 0; t < nt; ++t) {
      if ((tc++ & 7) != wave) continue;
      int base = segS + (t << 5);
      int i0 = base + l16, i1 = base + 16 + l16;
      unsigned int w0 = (i0 < segE) ? sorted[i0] : 0u;
      unsigned int w1 = (i1 < segE) ? sorted[i1] : 0u;
      int in0 = (int)(w0 >> 7), in1 = (int)(w1 >> 7);
      bf16x8 a[2][4];
      #pragma unroll
      for (int kb = 0; kb < 4; ++kb) {
        a[0][kb] = *(const bf16x8*)(fbf + (size_t)in0 * CIO + kb * 32 + lk * 8);
        a[1][kb] = *(const bf16x8*)(fbf + (size_t)in1 * CIO + kb * 32 + lk * 8);
      }
      #pragma unroll
      for (int h = 0; h < 2; ++h) {
        f32x4 acc[2][4] = {};
        #pragma unroll
        for (int kb = 0; kb < 4; ++kb) {
          const unsigned short* wkb = wk + kb * 4096 + h * 2048;
          #pragma unroll
          for (int nf = 0; nf < 4; ++nf) {
            bf16x8 bfr = *(const bf16x8*)(wkb + nf * 512 + lane * 8);
            acc[0][nf] = __builtin_amdgcn_mfma_f32_16x16x32_bf16(a[0][kb], bfr, acc[0][nf], 0, 0, 0);
            acc[1][nf] = __builtin_amdgcn_mfma_f32_16x16x32_bf16(a[1][kb], bfr, acc[1][nf], 0, 0, 0);
          }
        }
        #pragma unroll
        for (int rg = 0; rg < 2; ++rg) {
          unsigned int wsrc = rg ? w1 : w0;
          #pragma unroll
          for (int r = 0; r < 4; ++r) {
            int idx = base + rg * 16 + lk * 4 + r;
            if (idx < segE) {
              int lrow = (int)(__shfl(wsrc, lk * 4 + r) & 127u);
              float* dst = accum + lrow * 132 + h * 64 + l16;
              #pragma unroll
              for (int nf = 0; nf < 4; ++nf)
                atomicAdd(dst + nf * 16, acc[rg][nf][r]);
            }
          }
        }
      }
    }
  }
  __syncthreads();
  for (int i = tid; i < BR * 32; i += 512) {
    int row = i >> 5, c4 = i & 31;
    int orow = b * BR + row;
    if (orow < n_out) {
      float4v v  = *(const float4v*)(accum + row * 132 + c4 * 4);
      float4v bi = ((const float4v*)bias)[c4];
      v.x += bi.x; v.y += bi.y; v.z += bi.z; v.w += bi.w;
      *(float4v*)(out + (size_t)orow * CIO + c4 * 4) = v;
    }
  }
}

// ===================== legacy fallback (tiny ws) =====================
__global__ void prep_weights(const float* __restrict__ W,
                             unsigned short* __restrict__ Wt, int total) {
  int idx = blockIdx.x * 256 + threadIdx.x;
  if (idx >= total) return;
  int k  = idx >> 14;
  int n  = (idx >> 7) & 127;
  int kk = idx & 127;
  Wt[idx] = f2bf(W[k * 16384 + kk * 128 + n]);
}
__global__ void init_bias(float* __restrict__ out,
                          const float* __restrict__ bias, int total4) {
  int idx = blockIdx.x * 256 + threadIdx.x;
  if (idx >= total4) return;
  float4v b = ((const float4v*)bias)[idx & 31];
  ((float4v*)out)[idx] = b;
}
__global__ __launch_bounds__(256) void spconv_mfma_legacy(
    const float* __restrict__ features, const unsigned short* __restrict__ Wt,
    const int* __restrict__ in_map, const int* __restrict__ out_map,
    float* __restrict__ out, int M) {
  const int ky = blockIdx.y, m0 = blockIdx.x * 64, tid = threadIdx.x;
  __shared__ unsigned short Alds[64 * CIO];
  __shared__ unsigned short Blds[CIO * CIO];
  {
    const ushort8* src = (const ushort8*)(Wt + ky * 16384);
    #pragma unroll
    for (int i = 0; i < 8; ++i) {
      int chunk = tid + i * 256, byte = chunk * 16;
      int row = byte >> 8, off = byte & 255, sw = off ^ ((row & 7) << 4);
      *(ushort8*)((char*)Blds + row * 256 + sw) = src[chunk];
    }
  }
  {
    int r = tid >> 2, q = tid & 3, m = m0 + r;
    unsigned short tmp[32];
    if (m < M) {
      int frow = in_map[ky * M + m];
      const float4v* src = (const float4v*)(features + frow * CIO + q * 32);
      #pragma unroll
      for (int i = 0; i < 8; ++i) {
        float4v v = src[i];
        tmp[i*4+0]=f2bf(v.x); tmp[i*4+1]=f2bf(v.y); tmp[i*4+2]=f2bf(v.z); tmp[i*4+3]=f2bf(v.w);
      }
    } else {
      #pragma unroll
      for (int i = 0; i < 32; ++i) tmp[i] = 0;
    }
    #pragma unroll
    for (int c = 0; c < 4; ++c) {
      int off = q * 64 + c * 16, sw = off ^ ((r & 7) << 4);
      *(ushort8*)((char*)Alds + r * 256 + sw) = *(ushort8*)(tmp + c * 8);
    }
  }
  __syncthreads();
  const int wid = tid >> 6, lane = tid & 63;
  const int wm = wid >> 1, wn = wid & 1, l16 = lane & 15, lk = lane >> 4;
  f32x4 acc[2][4] = {};
  #pragma unroll
  for (int kb = 0; kb < CIO; kb += 32) {
    bf16x8 af[2], bfr[4];
    #pragma unroll
    for (int mf = 0; mf < 2; ++mf) {
      int row = wm * 32 + mf * 16 + l16, off = (kb + lk * 8) * 2;
      int sw = off ^ ((row & 7) << 4);
      af[mf] = *(const bf16x8*)((const char*)Alds + row * 256 + sw);
    }
    #pragma unroll
    for (int nf = 0; nf < 4; ++nf) {
      int n = wn * 64 + nf * 16 + l16, off = (kb + lk * 8) * 2;
      int sw = off ^ ((n & 7) << 4);
      bfr[nf] = *(const bf16x8*)((const char*)Blds + n * 256 + sw);
    }
    #pragma unroll
    for (int mf = 0; mf < 2; ++mf)
      #pragma unroll
      for (int nf = 0; nf < 4; ++nf)
        acc[mf][nf] = __builtin_amdgcn_mfma_f32_16x16x32_bf16(af[mf], bfr[nf], acc[mf][nf], 0, 0, 0);
  }
  #pragma unroll
  for (int mf = 0; mf < 2; ++mf)
    #pragma unroll
    for (int r = 0; r < 4; ++r) {
      int mrow = wm * 32 + mf * 16 + lk * 4 + r, m = m0 + mrow;
      if (m < M) {
        int orow = out_map[ky * M + m];
        float* dst = out + orow * CIO + wn * 64 + l16;
        #pragma unroll
        for (int nf = 0; nf < 4; ++nf) unsafeAtomicAdd(dst + nf * 16, acc[mf][nf][r]);
      }
    }
}

static inline size_t align256(size_t x) { return (x + 255) & ~(size_t)255; }

extern "C" void kernel_launch(void* const* d_in, const int* in_sizes, int n_in,
                              void* d_out, int out_size, void* d_ws, size_t ws_size,
                              hipStream_t stream) {
  const float* features = (const float*)d_in[0];
  const float* W        = (const float*)d_in[1];
  const float* bias     = (const float*)d_in[2];
  const int*   in_map   = (const int*)d_in[3];
  const int*   out_map  = (const int*)d_in[4];
  float*       out      = (float*)d_out;

  const int KVOL  = in_sizes[1] / (CIO * CIO);     // 27
  const int M     = in_sizes[3] / KVOL;            // 50000
  const int n_out = out_size / CIO;                // 100000
  const int N_IN  = in_sizes[0] / CIO;             // 100000
  const int NB    = (n_out + BR - 1) / BR;         // 834
  const int NKEY  = KVOL * NB;
  const size_t KM = (size_t)KVOL * M;

  const size_t s_wswz = (size_t)KVOL * CIO * CIO * 2;
  const size_t o_cnt  = align256(s_wswz);
  const size_t o_offs = align256(o_cnt + (size_t)NKEY * 4);
  const size_t o_sort = align256(o_offs + ((size_t)NKEY + 1) * 4);
  const size_t o_fbf  = align256(o_sort + KM * 4);
  const size_t o_prod = align256(o_fbf + (size_t)N_IN * CIO * 2);
  const size_t perk   = (size_t)M * CIO * 2;       // prod bytes per k (12.8 MB)

  int kper = 0;
  if (ws_size > o_prod) {
    size_t avail = ws_size - o_prod;
    kper = (int)(avail / perk);
    if (kper > KVOL) kper = KVOL;
  }

  if (NB <= NB_MAX && kper >= 1) {
    // ---------- two-phase path ----------
    unsigned short* Wswz   = (unsigned short*)d_ws;
    int*            cnt    = (int*)((char*)d_ws + o_cnt);
    int*            offs   = (int*)((char*)d_ws + o_offs);
    unsigned int*   sorted = (unsigned int*)((char*)d_ws + o_sort);
    unsigned short* fbf    = (unsigned short*)((char*)d_ws + o_fbf);
    unsigned short* prod   = (unsigned short*)((char*)d_ws + o_prod);

    int wtot = KVOL * 4 * 8 * 64;
    prep_wswz<<<(wtot + 255) / 256, 256, 0, stream>>>(W, Wswz, wtot);
    int total8 = N_IN * CIO / 8;
    prep_fbf<<<(total8 + 255) / 256, 256, 0, stream>>>(features, fbf, total8);
    count27<<<KVOL, 1024, 0, stream>>>(out_map, cnt, M, NB);
    scan_offsets<<<1, 1024, 0, stream>>>(cnt, offs, NKEY);
    scatter27<<<KVOL, 1024, 0, stream>>>(in_map, out_map, offs, sorted, M, NB);

    const int TPK = (M + 31) / 32;
    for (int k0 = 0; k0 < KVOL; k0 += kper) {
      int k1 = min(k0 + kper, KVOL);
      int nk = k1 - k0;
      int blocksA = (nk * TPK + 3) / 4;
      spconv_prod<<<blocksA, 256, 0, stream>>>(fbf, Wswz, sorted, prod, M, TPK, k0, k1);
      spconv_reduce<<<NB, 256, 0, stream>>>(prod, sorted, offs, bias, out,
                                            NB, n_out, M, k0, k1, (k0 > 0) ? 1 : 0);
    }
  } else if (NB <= NB_MAX && ws_size >= o_prod) {
    // ---------- R5 CSR fallback ----------
    unsigned short* Wswz   = (unsigned short*)d_ws;
    int*            cnt    = (int*)((char*)d_ws + o_cnt);
    int*            offs   = (int*)((char*)d_ws + o_offs);
    unsigned int*   sorted = (unsigned int*)((char*)d_ws + o_sort);
    unsigned short* fbf    = (unsigned short*)((char*)d_ws + o_fbf);
    int wtot = KVOL * 4 * 8 * 64;
    prep_wswz<<<(wtot + 255) / 256, 256, 0, stream>>>(W, Wswz, wtot);
    int total8 = N_IN * CIO / 8;
    prep_fbf<<<(total8 + 255) / 256, 256, 0, stream>>>(features, fbf, total8);
    count27<<<KVOL, 1024, 0, stream>>>(out_map, cnt, M, NB);
    scan_offsets<<<1, 1024, 0, stream>>>(cnt, offs, NKEY);
    scatter27<<<KVOL, 1024, 0, stream>>>(in_map, out_map, offs, sorted, M, NB);
    spconv_csr<true><<<NB, 512, 0, stream>>>(features, fbf, Wswz, sorted, offs,
                                             bias, out, NB, n_out, KVOL);
  } else {
    // ---------- legacy tiny-ws fallback ----------
    unsigned short* Wt = (unsigned short*)d_ws;
    if (ws_size < s_wswz) return;
    int wtot = KVOL * CIO * CIO;
    prep_weights<<<(wtot + 255) / 256, 256, 0, stream>>>(W, Wt, wtot);
    int total4 = out_size / 4;
    init_bias<<<(total4 + 255) / 256, 256, 0, stream>>>(out, bias, total4);
    dim3 grid((M + 63) / 64, KVOL);
    spconv_mfma_legacy<<<grid, 256, 0, stream>>>(features, Wt, in_map, out_map, out, M);
  }
}